// Round 10
// baseline (472.872 us; speedup 1.0000x reference)
//
#include <hip/hip_runtime.h>
#include <math.h>

// Shapes: B=2, T=2048, D=1024, H=8, S=32, Dh=128, 3D=3072, B*T=4096
// POLISH R27: base = R9 (465.2us PASS; combine eliminated, flash v11 full-j).
// Single change-set: QKV GEMM epilogue now emits bf16 q16/k16 (row-major) and
// pre-transposed vt16 directly (values = f2bf of the f32 MFMA result, i.e.
// bit-identical to what splat_tv produced). The f32 qT/kT/vT intermediates,
// splat's f2bf work, and the entire 4096-block transpose branch are deleted
// (~84MB traffic). Only numeric delta: splat's sq is now computed from
// bf16-rounded q/k (delta-d2 ~0.09, same order as existing bf16-dot error;
// absmax headroom 3.6x).

typedef __attribute__((ext_vector_type(8))) short s16x8;
typedef __attribute__((ext_vector_type(4))) short s16x4;
typedef __attribute__((ext_vector_type(4))) float f32x4;

__device__ inline short f2bf(float f) {
  union { float f; unsigned u; } v; v.f = f;
  unsigned r = v.u + 0x7FFFu + ((v.u >> 16) & 1u);
  return (short)(r >> 16);
}
__device__ inline float bf2f(short s) {
  union { unsigned u; float f; } v;
  v.u = ((unsigned)(unsigned short)s) << 16;
  return v.f;
}
// Packed f32x2 -> bf16x2, RNE (identical rounding to f2bf).
__device__ inline unsigned cvt_pk_bf16(float lo, float hi) {
  unsigned r;
  asm("v_cvt_pk_bf16_f32 %0, %1, %2" : "=v"(r) : "v"(lo), "v"(hi));
  return r;
}
#define MFMA_BF16(a, b, c) __builtin_amdgcn_mfma_f32_16x16x32_bf16((a), (b), (c), 0, 0, 0)

// Async global->LDS, 16B per lane. LDS dest is wave-uniform base + lane*16.
#define GLOAD_LDS16(gsrc, ldst)                                          \
  __builtin_amdgcn_global_load_lds(                                      \
      (const __attribute__((address_space(1))) void*)(gsrc),             \
      (__attribute__((address_space(3))) void*)(ldst), 16, 0, 0)

// ---------------------------------------------------------------------------
// Fused prep (round-8 exact).
// ---------------------------------------------------------------------------
__device__ inline void transpose_tile32(const float* __restrict__ W,
                                        short* __restrict__ Wt, int K, int N,
                                        int n0, int k0) {
  __shared__ float tile[32][33];
  const int r = threadIdx.x >> 3, c4 = (threadIdx.x & 7) * 4;
  float4 v = *(const float4*)(W + (size_t)(k0 + r) * N + n0 + c4);
  tile[r][c4 + 0] = v.x; tile[r][c4 + 1] = v.y;
  tile[r][c4 + 2] = v.z; tile[r][c4 + 3] = v.w;
  __syncthreads();
  s16x4 o;
  o[0] = f2bf(tile[c4 + 0][r]);
  o[1] = f2bf(tile[c4 + 1][r]);
  o[2] = f2bf(tile[c4 + 2][r]);
  o[3] = f2bf(tile[c4 + 3][r]);
  *(s16x4*)(Wt + (size_t)(n0 + r) * K + k0 + c4) = o;
}

__global__ __launch_bounds__(256) void prep_fused(
    const float* __restrict__ x, short* __restrict__ x16,
    const float* __restrict__ Wqkv, short* __restrict__ Wqt16,
    const float* __restrict__ Wout, short* __restrict__ Wot16,
    const float* __restrict__ ctr, const float* __restrict__ ls,
    const float* __restrict__ la, short* __restrict__ c16,
    float* __restrict__ csq, float* __restrict__ inv2, float* __restrict__ amp) {
  const int bx = blockIdx.x;
  if (bx < 4096) {
    int i = bx * 256 + threadIdx.x;
    float4 v = ((const float4*)x)[i];
    s16x4 o;
    o[0] = f2bf(v.x); o[1] = f2bf(v.y); o[2] = f2bf(v.z); o[3] = f2bf(v.w);
    ((s16x4*)x16)[i] = o;
  } else if (bx < 7168) {
    int idx = bx - 4096;
    transpose_tile32(Wqkv, Wqt16, 1024, 3072, (idx % 96) * 32, (idx / 96) * 32);
  } else if (bx < 8192) {
    int idx = bx - 7168;
    transpose_tile32(Wout, Wot16, 1024, 1024, (idx % 32) * 32, (idx / 32) * 32);
  } else {
    const int t = threadIdx.x;
    float sumsq = 0.f;
#pragma unroll
    for (int d = 0; d < 128; d += 4) {
      float4 v = *(const float4*)(ctr + (size_t)t * 128 + d);
      sumsq += v.x * v.x + v.y * v.y + v.z * v.z + v.w * v.w;
      s16x4 o;
      o[0] = f2bf(v.x); o[1] = f2bf(v.y); o[2] = f2bf(v.z); o[3] = f2bf(v.w);
      *(s16x4*)(c16 + (size_t)t * 128 + d) = o;
    }
    csq[t] = sumsq;
    float sc = __expf(ls[t]);
    float iv = 1.0f / (sc + 1e-6f);
    inv2[t] = -0.5f * iv * iv;
    amp[t] = __expf(la[t]);
  }
}

// ---------------------------------------------------------------------------
// bf16 MFMA GEMM, m97-style LDS staging — QKV.
// SCATTER epilogue now emits bf16 directly: q16/k16 row-major, vt16 transposed.
// ---------------------------------------------------------------------------
template <int N, bool SCATTER>
__global__ __launch_bounds__(256) void gemm_bf16(
    const short* __restrict__ A, const short* __restrict__ Wt,
    const float* __restrict__ bias,
    short* __restrict__ q16, short* __restrict__ k16, short* __restrict__ vt16,
    float* __restrict__ outf) {
  __shared__ short As[128 * 64];
  __shared__ short Bs[128 * 64];
  const int tid = threadIdx.x;
  const int w = tid >> 6, l = tid & 63;
  const int lm = l & 15, lk = l >> 4;
  const int bn0 = blockIdx.x * 128;
  const int bm0 = blockIdx.y * 128;
  const int n0 = bn0 + (w & 1) * 64;
  const int m0 = bm0 + (w >> 1) * 64;
  const int K = 1024;
  f32x4 acc[4][4];
#pragma unroll
  for (int mi = 0; mi < 4; mi++)
#pragma unroll
    for (int ni = 0; ni < 4; ni++) acc[mi][ni] = (f32x4){0.f, 0.f, 0.f, 0.f};

  const int srow = l >> 3;
  const int scol = (l & 7) * 8;
  const int mh = (w >> 1) * 64, nh = (w & 1) * 64;

  for (int k0 = 0; k0 < K; k0 += 64) {
#pragma unroll
    for (int q = 0; q < 4; q++) {
      const int chunk = w * 4 + q;
      const int row = chunk * 8 + srow;
      GLOAD_LDS16(A + (size_t)(bm0 + row) * K + k0 + scol, As + chunk * 512);
      GLOAD_LDS16(Wt + (size_t)(bn0 + row) * K + k0 + scol, Bs + chunk * 512);
    }
    __syncthreads();
#pragma unroll
    for (int kk = 0; kk < 2; kk++) {
      s16x8 af[4], bf[4];
#pragma unroll
      for (int i = 0; i < 4; i++) {
        af[i] = *(const s16x8*)(As + (mh + i * 16 + lm) * 64 + kk * 32 + lk * 8);
        bf[i] = *(const s16x8*)(Bs + (nh + i * 16 + lm) * 64 + kk * 32 + lk * 8);
      }
#pragma unroll
      for (int mi = 0; mi < 4; mi++)
#pragma unroll
        for (int ni = 0; ni < 4; ni++)
          acc[mi][ni] = MFMA_BF16(af[mi], bf[ni], acc[mi][ni]);
    }
    __syncthreads();
  }
#pragma unroll
  for (int ni = 0; ni < 4; ni++) {
    const int n = n0 + ni * 16 + lm;
    const float bv = bias[n];
#pragma unroll
    for (int mi = 0; mi < 4; mi++) {
#pragma unroll
      for (int r = 0; r < 4; r++) {
        const int m = m0 + mi * 16 + lk * 4 + r;
        float v = acc[mi][ni][r] + bv;
        if (SCATTER) {
          int three = n >> 10;
          int h = (n >> 7) & 7;
          int dh = n & 127;
          int bb = m >> 11, tt = m & 2047;
          int bh = bb * 8 + h;
          if (three == 0)
            q16[((size_t)bh * 2048 + tt) * 128 + dh] = f2bf(v);
          else if (three == 1)
            k16[((size_t)bh * 2048 + tt) * 128 + dh] = f2bf(v);
          else
            vt16[((size_t)(bh * 128 + dh)) * 2048 + tt] = f2bf(v);
        } else {
          outf[(size_t)m * N + n] = v;
        }
      }
    }
  }
}

// ---------------------------------------------------------------------------
// splat: q/k weights via MFMA against centers (1024 blocks; transpose branch
// and all f32 intermediates deleted). af fragments are bit-identical to the
// old path (bf16 values produced by the GEMM epilogue's f2bf).
// ---------------------------------------------------------------------------
__global__ __launch_bounds__(256) void splat_tv(
    const short* __restrict__ q16, const short* __restrict__ k16,
    const short* __restrict__ c16, const float* __restrict__ csq,
    const float* __restrict__ inv2, const float* __restrict__ amp,
    short* __restrict__ qa16, short* __restrict__ kw16) {
  const int tid = threadIdx.x;
  const int it = blockIdx.x & 31;
  const int bh = (blockIdx.x >> 5) & 15;
  const int which = blockIdx.x >> 9;
  const int w = tid >> 6, l = tid & 63;
  const int lm = l & 15, lk = l >> 4;
  const int h = bh & 7;
  const int i0 = it * 64 + w * 16;
  const short* src = which ? k16 : q16;

  s16x8 af[4];
  float sq = 0.f;
#pragma unroll
  for (int kk = 0; kk < 4; kk++) {
    af[kk] = *(const s16x8*)(src + ((size_t)bh * 2048 + i0 + lm) * 128 + kk * 32 + lk * 8);
#pragma unroll
    for (int j = 0; j < 8; j++) {
      float f = bf2f(af[kk][j]);
      sq += f * f;
    }
  }
  sq += __shfl_xor(sq, 16);
  sq += __shfl_xor(sq, 32);

  f32x4 acc[2];
  acc[0] = (f32x4){0.f, 0.f, 0.f, 0.f};
  acc[1] = (f32x4){0.f, 0.f, 0.f, 0.f};
#pragma unroll
  for (int kk = 0; kk < 4; kk++) {
    s16x8 b0 = *(const s16x8*)(c16 + (size_t)(h * 32 + lm) * 128 + kk * 32 + lk * 8);
    s16x8 b1 = *(const s16x8*)(c16 + (size_t)(h * 32 + 16 + lm) * 128 + kk * 32 + lk * 8);
    acc[0] = MFMA_BF16(af[kk], b0, acc[0]);
    acc[1] = MFMA_BF16(af[kk], b1, acc[1]);
  }
  short* dst = which ? kw16 : qa16;
#pragma unroll
  for (int ni = 0; ni < 2; ni++) {
    const int n = ni * 16 + lm;
    const float cs = csq[h * 32 + n];
    const float iv2 = inv2[h * 32 + n];
    const float am = which ? 1.0f : amp[h * 32 + n];
#pragma unroll
    for (int r = 0; r < 4; r++) {
      float qs = __shfl(sq, lk * 4 + r);
      float d2 = fmaxf(qs + cs - 2.0f * acc[ni][r], 0.0f);
      float wv = __expf(iv2 * d2) * am;
      int m = i0 + lk * 4 + r;
      dst[((size_t)bh * 2048 + m) * 32 + n] = f2bf(wv);
    }
  }
}

// ---------------------------------------------------------------------------
// Flash attention v11 (R9 exact): sigma-relabeled swapped-QK + LDS-staged V
// dbuf, full j-range, fused normalize -> direct aout16/lrow write.
// ---------------------------------------------------------------------------
__global__ __launch_bounds__(256) void attn_flash(
    const short* __restrict__ qa16, const short* __restrict__ kw16,
    const short* __restrict__ vt16, const float* __restrict__ temp,
    float* __restrict__ lrow, short* __restrict__ aout16) {
  __shared__ short Vs[2][8192];  // 2 x 16KB: [128 rows][8 slots of 16B]
  const int tid = threadIdx.x;
  const int w = tid >> 6, l = tid & 63;
  const int lm = l & 15, lk = l >> 4;
  const int it = blockIdx.x, h = blockIdx.y;
  const int b = blockIdx.z;
  const int bh = b * 8 + h;
  const int i0 = it * 64 + w * 16;
  const float invT = 1.0f / temp[0];
  const short* kwb = kw16 + (size_t)bh * 2048 * 32;
  const short* vtb = vt16 + (size_t)bh * 128 * 2048;
  s16x8 qfrag = *(const s16x8*)(qa16 + ((size_t)(bh * 2048 + i0 + lm)) * 32 + lk * 8);
  float lsum = 0.f;
  f32x4 acc[8];
#pragma unroll
  for (int d = 0; d < 8; d++) acc[d] = (f32x4){0.f, 0.f, 0.f, 0.f};

  const int sig0 = (lm >> 2) * 8 + (lm & 3);
  const int srow8 = l >> 3;
  const int scb = (l & 7) ^ srow8;
  const int rcb0 = (lk ^ (lm & 7)) * 8;
  const int rcb1 = ((lk + 4) ^ (lm & 7)) * 8;

#pragma unroll
  for (int q = 0; q < 4; q++) {
    const int chunk = w * 4 + q;
    GLOAD_LDS16(vtb + (size_t)(chunk * 8 + srow8) * 2048 + scb * 8,
                &Vs[0][chunk * 512]);
  }
  __syncthreads();

  int cur = 0;
  for (int jc = 0; jc < 2048; jc += 64) {
    if (jc + 64 < 2048) {
#pragma unroll
      for (int q = 0; q < 4; q++) {
        const int chunk = w * 4 + q;
        GLOAD_LDS16(vtb + (size_t)(chunk * 8 + srow8) * 2048 + (jc + 64) + scb * 8,
                    &Vs[cur ^ 1][chunk * 512]);
      }
    }
    s16x8 kb[4];
    kb[0] = *(const s16x8*)(kwb + (size_t)(jc + sig0) * 32 + lk * 8);
    kb[1] = *(const s16x8*)(kwb + (size_t)(jc + sig0 + 4) * 32 + lk * 8);
    kb[2] = *(const s16x8*)(kwb + (size_t)(jc + sig0 + 32) * 32 + lk * 8);
    kb[3] = *(const s16x8*)(kwb + (size_t)(jc + sig0 + 36) * 32 + lk * 8);
    f32x4 z = (f32x4){0.f, 0.f, 0.f, 0.f};
    f32x4 s[4];
#pragma unroll
    for (int c = 0; c < 4; c++) s[c] = MFMA_BF16(kb[c], qfrag, z);
    float p[4][4];
#pragma unroll
    for (int c = 0; c < 4; c++) {
      p[c][0] = __expf(s[c][0] * invT);
      p[c][1] = __expf(s[c][1] * invT);
      p[c][2] = __expf(s[c][2] * invT);
      p[c][3] = __expf(s[c][3] * invT);
      lsum += (p[c][0] + p[c][1]) + (p[c][2] + p[c][3]);
    }
    union { unsigned u[4]; s16x8 v; } t0, t1;
    t0.u[0] = cvt_pk_bf16(p[0][0], p[0][1]);
    t0.u[1] = cvt_pk_bf16(p[0][2], p[0][3]);
    t0.u[2] = cvt_pk_bf16(p[1][0], p[1][1]);
    t0.u[3] = cvt_pk_bf16(p[1][2], p[1][3]);
    t1.u[0] = cvt_pk_bf16(p[2][0], p[2][1]);
    t1.u[1] = cvt_pk_bf16(p[2][2], p[2][3]);
    t1.u[2] = cvt_pk_bf16(p[3][0], p[3][1]);
    t1.u[3] = cvt_pk_bf16(p[3][2], p[3][3]);
    s16x8 pf0 = t0.v, pf1 = t1.v;
    const short* vb = Vs[cur];
#pragma unroll
    for (int d = 0; d < 8; d++) {
      const short* vsrow = vb + (d * 16 + lm) * 64;
      s16x8 vb0 = *(const s16x8*)(vsrow + rcb0);
      s16x8 vb1 = *(const s16x8*)(vsrow + rcb1);
      acc[d] = MFMA_BF16(pf0, vb0, acc[d]);
      acc[d] = MFMA_BF16(pf1, vb1, acc[d]);
    }
    __syncthreads();
    cur ^= 1;
  }
  lsum += __shfl_xor(lsum, 16);
  lsum += __shfl_xor(lsum, 32);
  if (l < 16) lrow[bh * 2048 + i0 + l] = lsum;
  float invl[4];
#pragma unroll
  for (int r = 0; r < 4; r++) invl[r] = 1.0f / __shfl(lsum, lk * 4 + r);
  short* ob = aout16 + ((size_t)(b * 2048 + i0)) * 1024 + h * 128 + lm;
#pragma unroll
  for (int r = 0; r < 4; r++) {
    const int row = lk * 4 + r;
#pragma unroll
    for (int d = 0; d < 8; d++)
      ob[(size_t)row * 1024 + d * 16] = f2bf(acc[d][r] * invl[r]);
  }
}

// ---------------------------------------------------------------------------
// gemm_out: standalone out-projection (R5 exact).
// ---------------------------------------------------------------------------
__global__ __launch_bounds__(256) void gemm_out(
    const short* __restrict__ aout16, const short* __restrict__ Wot16,
    const float* __restrict__ bout, float* __restrict__ out) {
  __shared__ short As[128 * 64];
  __shared__ short Bs[128 * 64];
  const int tid = threadIdx.x;
  const int w = tid >> 6, l = tid & 63;
  const int lm = l & 15, lk = l >> 4;
  const int idx = blockIdx.x;
  const int bn0 = (idx & 7) * 128;
  const int bm0 = (idx >> 3) * 128;
  const int n0 = bn0 + (w & 1) * 64;
  const int m0 = bm0 + (w >> 1) * 64;
  const int K = 1024;
  f32x4 acc[4][4];
#pragma unroll
  for (int mi = 0; mi < 4; mi++)
#pragma unroll
    for (int ni = 0; ni < 4; ni++) acc[mi][ni] = (f32x4){0.f, 0.f, 0.f, 0.f};
  const int srow = l >> 3;
  const int scol = (l & 7) * 8;
  const int mh = (w >> 1) * 64, nh = (w & 1) * 64;
  for (int k0 = 0; k0 < K; k0 += 64) {
#pragma unroll
    for (int q = 0; q < 4; q++) {
      const int chunk = w * 4 + q;
      const int row = chunk * 8 + srow;
      GLOAD_LDS16(aout16 + (size_t)(bm0 + row) * K + k0 + scol, As + chunk * 512);
      GLOAD_LDS16(Wot16 + (size_t)(bn0 + row) * K + k0 + scol, Bs + chunk * 512);
    }
    __syncthreads();
#pragma unroll
    for (int kk = 0; kk < 2; kk++) {
      s16x8 af[4], bf[4];
#pragma unroll
      for (int i = 0; i < 4; i++) {
        af[i] = *(const s16x8*)(As + (mh + i * 16 + lm) * 64 + kk * 32 + lk * 8);
        bf[i] = *(const s16x8*)(Bs + (nh + i * 16 + lm) * 64 + kk * 32 + lk * 8);
      }
#pragma unroll
      for (int mi = 0; mi < 4; mi++)
#pragma unroll
        for (int ni = 0; ni < 4; ni++)
          acc[mi][ni] = MFMA_BF16(af[mi], bf[ni], acc[mi][ni]);
    }
    __syncthreads();
  }
#pragma unroll
  for (int ni = 0; ni < 4; ni++) {
    const int n = n0 + ni * 16 + lm;
    const float bv = bout[n];
#pragma unroll
    for (int mi = 0; mi < 4; mi++) {
#pragma unroll
      for (int r = 0; r < 4; r++) {
        const int m = m0 + mi * 16 + lk * 4 + r;
        out[(size_t)m * 1024 + n] = acc[mi][ni][r] + bv;
      }
    }
  }
}

// ---------------------------------------------------------------------------
// attn_write: standalone, 16x32 tiles (R5 exact).
// ---------------------------------------------------------------------------
__global__ __launch_bounds__(256) void attn_write(
    const short* __restrict__ qa16, const short* __restrict__ kw16,
    const float* __restrict__ lrow, const float* __restrict__ temp,
    float* __restrict__ attn) {
  __shared__ float pl[8][16][33];
  const int tid = threadIdx.x;
  const int w = tid >> 6, l = tid & 63;
  const int lm = l & 15, lk = l >> 4;
  const int bx = blockIdx.x;
  const int i0 = (bx & 127) * 16;
  const int j0 = ((bx >> 7) & 63) * 32;
  const int b = bx >> 13;
  const float invT = 1.0f / temp[0];
#pragma unroll
  for (int hh = 0; hh < 2; hh++) {
    const int h = w * 2 + hh;
    const int bh = b * 8 + h;
    s16x8 qf = *(const s16x8*)(qa16 + ((size_t)(bh * 2048 + i0 + lm)) * 32 + lk * 8);
    s16x8 kf[2];
#pragma unroll
    for (int jh = 0; jh < 2; jh++)
      kf[jh] = *(const s16x8*)(kw16 + ((size_t)(bh * 2048 + j0 + jh * 16 + lm)) * 32 + lk * 8);
    float il[4];
#pragma unroll
    for (int r = 0; r < 4; r++)
      il[r] = 1.0f / lrow[bh * 2048 + i0 + lk * 4 + r];
    f32x4 z = (f32x4){0.f, 0.f, 0.f, 0.f};
#pragma unroll
    for (int jh = 0; jh < 2; jh++) {
      f32x4 s = MFMA_BF16(qf, kf[jh], z);
#pragma unroll
      for (int r = 0; r < 4; r++) {
        float p = __expf(s[r] * invT) * il[r];
        pl[h][lk * 4 + r][jh * 16 + lm] = p;
      }
    }
  }
  __syncthreads();
#pragma unroll
  for (int c = 0; c < 4; c++) {
    int u = c * 256 + tid;
    int i = u >> 6, rem = u & 63;
    int j = rem >> 1, h4 = (rem & 1) * 4;
    f32x4 v;
    v[0] = pl[h4][i][j];
    v[1] = pl[h4 + 1][i][j];
    v[2] = pl[h4 + 2][i][j];
    v[3] = pl[h4 + 3][i][j];
    f32x4* dst = (f32x4*)(attn + (((size_t)(b * 2048 + i0 + i)) * 2048 + j0 + j) * 8 + h4);
    __builtin_nontemporal_store(v, dst);
  }
}

// ---------------------------------------------------------------------------
extern "C" void kernel_launch(void* const* d_in, const int* in_sizes, int n_in,
                              void* d_out, int out_size, void* d_ws, size_t ws_size,
                              hipStream_t stream) {
  const float* x    = (const float*)d_in[0];
  const float* Wqkv = (const float*)d_in[1];
  const float* bqkv = (const float*)d_in[2];
  const float* Wout = (const float*)d_in[3];
  const float* bout = (const float*)d_in[4];
  const float* ctr  = (const float*)d_in[5];
  const float* ls   = (const float*)d_in[6];
  const float* la   = (const float*)d_in[7];
  const float* temp = (const float*)d_in[8];

  float* out = (float*)d_out;                 // (B,T,D)
  float* attn = out + 4194304;                // (B,T,T,H)

  short* ws16 = (short*)d_ws;
  short* q16   = ws16;                        // 4,194,304 sh (B,H,T,Dh) bf16
  short* k16   = q16 + 4194304;               // 4,194,304 sh
  short* vt16  = k16 + 4194304;               // 4,194,304 sh (B,H,Dh,T) bf16
  short* x16   = vt16 + 4194304;              // 4,194,304 sh
  short* Wqt16 = x16 + 4194304;               // 3,145,728 sh
  short* Wot16 = Wqt16 + 3145728;             // 1,048,576 sh
  short* qa16  = Wot16 + 1048576;             // 1,048,576 sh
  short* kw16  = qa16 + 1048576;              // 1,048,576 sh
  short* aout16 = kw16 + 1048576;             // 4,194,304 sh
  short* c16   = aout16 + 4194304;            // 32,768 sh
  float* lrow  = (float*)(c16 + 32768);       // 32,768 fl
  float* csq   = lrow + 32768;                // 256
  float* inv2  = csq + 256;
  float* amp   = inv2 + 256;

  prep_fused<<<8193, 256, 0, stream>>>(x, x16, Wqkv, Wqt16, Wout, Wot16,
                                       ctr, ls, la, c16, csq, inv2, amp);
  gemm_bf16<3072, true><<<dim3(24, 32), 256, 0, stream>>>(
      x16, Wqt16, bqkv, q16, k16, vt16, nullptr);
  splat_tv<<<1024, 256, 0, stream>>>(
      q16, k16, c16, csq, inv2, amp, qa16, kw16);
  attn_flash<<<dim3(32, 8, 2), 256, 0, stream>>>(
      qa16, kw16, vt16, temp, lrow, aout16);
  gemm_out<<<256, 256, 0, stream>>>(aout16, Wot16, bout, out);
  attn_write<<<16384, 256, 0, stream>>>(qa16, kw16, lrow, temp, attn);
}

// Round 12
// 458.753 us; speedup vs baseline: 1.0308x; 1.0308x over previous
//
#include <hip/hip_runtime.h>
#include <math.h>

// Shapes: B=2, T=2048, D=1024, H=8, S=32, Dh=128, 3D=3072, B*T=4096
// POLISH R28 (resubmit — R11 bench was a GPUAcquisitionTimeout, no data).
// base = R10 (472.9us PASS; bf16-direct QKV epilogue, transpose branch
// deleted). R10 regressed +7.7 vs R9 because the v-third epilogue stored
// vt16 as a transposed 2-byte scatter (lanes 4KB apart). Fix: for v blocks,
// stage the 128x128 tile in LDS n-major (stride 136 -> 2-way bank alias =
// free), then write coalesced s16x8 rows (16 lanes = 256B contiguous).
// q/k direct row-major bf16 stores and all R10 deletions kept.

typedef __attribute__((ext_vector_type(8))) short s16x8;
typedef __attribute__((ext_vector_type(4))) short s16x4;
typedef __attribute__((ext_vector_type(4))) float f32x4;

__device__ inline short f2bf(float f) {
  union { float f; unsigned u; } v; v.f = f;
  unsigned r = v.u + 0x7FFFu + ((v.u >> 16) & 1u);
  return (short)(r >> 16);
}
__device__ inline float bf2f(short s) {
  union { unsigned u; float f; } v;
  v.u = ((unsigned)(unsigned short)s) << 16;
  return v.f;
}
// Packed f32x2 -> bf16x2, RNE (identical rounding to f2bf).
__device__ inline unsigned cvt_pk_bf16(float lo, float hi) {
  unsigned r;
  asm("v_cvt_pk_bf16_f32 %0, %1, %2" : "=v"(r) : "v"(lo), "v"(hi));
  return r;
}
#define MFMA_BF16(a, b, c) __builtin_amdgcn_mfma_f32_16x16x32_bf16((a), (b), (c), 0, 0, 0)

// Async global->LDS, 16B per lane. LDS dest is wave-uniform base + lane*16.
#define GLOAD_LDS16(gsrc, ldst)                                          \
  __builtin_amdgcn_global_load_lds(                                      \
      (const __attribute__((address_space(1))) void*)(gsrc),             \
      (__attribute__((address_space(3))) void*)(ldst), 16, 0, 0)

// ---------------------------------------------------------------------------
// Fused prep (round-8 exact).
// ---------------------------------------------------------------------------
__device__ inline void transpose_tile32(const float* __restrict__ W,
                                        short* __restrict__ Wt, int K, int N,
                                        int n0, int k0) {
  __shared__ float tile[32][33];
  const int r = threadIdx.x >> 3, c4 = (threadIdx.x & 7) * 4;
  float4 v = *(const float4*)(W + (size_t)(k0 + r) * N + n0 + c4);
  tile[r][c4 + 0] = v.x; tile[r][c4 + 1] = v.y;
  tile[r][c4 + 2] = v.z; tile[r][c4 + 3] = v.w;
  __syncthreads();
  s16x4 o;
  o[0] = f2bf(tile[c4 + 0][r]);
  o[1] = f2bf(tile[c4 + 1][r]);
  o[2] = f2bf(tile[c4 + 2][r]);
  o[3] = f2bf(tile[c4 + 3][r]);
  *(s16x4*)(Wt + (size_t)(n0 + r) * K + k0 + c4) = o;
}

__global__ __launch_bounds__(256) void prep_fused(
    const float* __restrict__ x, short* __restrict__ x16,
    const float* __restrict__ Wqkv, short* __restrict__ Wqt16,
    const float* __restrict__ Wout, short* __restrict__ Wot16,
    const float* __restrict__ ctr, const float* __restrict__ ls,
    const float* __restrict__ la, short* __restrict__ c16,
    float* __restrict__ csq, float* __restrict__ inv2, float* __restrict__ amp) {
  const int bx = blockIdx.x;
  if (bx < 4096) {
    int i = bx * 256 + threadIdx.x;
    float4 v = ((const float4*)x)[i];
    s16x4 o;
    o[0] = f2bf(v.x); o[1] = f2bf(v.y); o[2] = f2bf(v.z); o[3] = f2bf(v.w);
    ((s16x4*)x16)[i] = o;
  } else if (bx < 7168) {
    int idx = bx - 4096;
    transpose_tile32(Wqkv, Wqt16, 1024, 3072, (idx % 96) * 32, (idx / 96) * 32);
  } else if (bx < 8192) {
    int idx = bx - 7168;
    transpose_tile32(Wout, Wot16, 1024, 1024, (idx % 32) * 32, (idx / 32) * 32);
  } else {
    const int t = threadIdx.x;
    float sumsq = 0.f;
#pragma unroll
    for (int d = 0; d < 128; d += 4) {
      float4 v = *(const float4*)(ctr + (size_t)t * 128 + d);
      sumsq += v.x * v.x + v.y * v.y + v.z * v.z + v.w * v.w;
      s16x4 o;
      o[0] = f2bf(v.x); o[1] = f2bf(v.y); o[2] = f2bf(v.z); o[3] = f2bf(v.w);
      *(s16x4*)(c16 + (size_t)t * 128 + d) = o;
    }
    csq[t] = sumsq;
    float sc = __expf(ls[t]);
    float iv = 1.0f / (sc + 1e-6f);
    inv2[t] = -0.5f * iv * iv;
    amp[t] = __expf(la[t]);
  }
}

// ---------------------------------------------------------------------------
// bf16 MFMA GEMM, m97-style LDS staging — QKV.
// q/k: direct row-major bf16 stores. v: LDS-transposed coalesced s16x8 rows.
// ---------------------------------------------------------------------------
template <int N, bool SCATTER>
__global__ __launch_bounds__(256) void gemm_bf16(
    const short* __restrict__ A, const short* __restrict__ Wt,
    const float* __restrict__ bias,
    short* __restrict__ q16, short* __restrict__ k16, short* __restrict__ vt16,
    float* __restrict__ outf) {
  __shared__ union {
    struct { short As[128 * 64]; short Bs[128 * 64]; } s;  // 32 KB
    short tv[128 * 136];                                   // 34 KB (v-transpose)
  } sm;
  const int tid = threadIdx.x;
  const int w = tid >> 6, l = tid & 63;
  const int lm = l & 15, lk = l >> 4;
  const int bn0 = blockIdx.x * 128;
  const int bm0 = blockIdx.y * 128;
  const int n0 = bn0 + (w & 1) * 64;
  const int m0 = bm0 + (w >> 1) * 64;
  const int K = 1024;
  f32x4 acc[4][4];
#pragma unroll
  for (int mi = 0; mi < 4; mi++)
#pragma unroll
    for (int ni = 0; ni < 4; ni++) acc[mi][ni] = (f32x4){0.f, 0.f, 0.f, 0.f};

  const int srow = l >> 3;
  const int scol = (l & 7) * 8;
  const int mh = (w >> 1) * 64, nh = (w & 1) * 64;

  for (int k0 = 0; k0 < K; k0 += 64) {
#pragma unroll
    for (int q = 0; q < 4; q++) {
      const int chunk = w * 4 + q;
      const int row = chunk * 8 + srow;
      GLOAD_LDS16(A + (size_t)(bm0 + row) * K + k0 + scol, sm.s.As + chunk * 512);
      GLOAD_LDS16(Wt + (size_t)(bn0 + row) * K + k0 + scol, sm.s.Bs + chunk * 512);
    }
    __syncthreads();
#pragma unroll
    for (int kk = 0; kk < 2; kk++) {
      s16x8 af[4], bf[4];
#pragma unroll
      for (int i = 0; i < 4; i++) {
        af[i] = *(const s16x8*)(sm.s.As + (mh + i * 16 + lm) * 64 + kk * 32 + lk * 8);
        bf[i] = *(const s16x8*)(sm.s.Bs + (nh + i * 16 + lm) * 64 + kk * 32 + lk * 8);
      }
#pragma unroll
      for (int mi = 0; mi < 4; mi++)
#pragma unroll
        for (int ni = 0; ni < 4; ni++)
          acc[mi][ni] = MFMA_BF16(af[mi], bf[ni], acc[mi][ni]);
    }
    __syncthreads();
  }
  if (SCATTER) {
    const int three = bn0 >> 10;
    if (three < 2) {
      // q/k: direct row-major bf16 stores (R10 path, proven).
      short* dst0 = three ? k16 : q16;
      const int h = (bn0 >> 7) & 7;
      const int bb = bm0 >> 11;
      const int bh = bb * 8 + h;
      const int tt0 = bm0 & 2047;
#pragma unroll
      for (int ni = 0; ni < 4; ni++) {
        const int n = n0 + ni * 16 + lm;
        const int dh = n & 127;
        const float bv = bias[n];
#pragma unroll
        for (int mi = 0; mi < 4; mi++) {
#pragma unroll
          for (int r = 0; r < 4; r++) {
            const int ml = mh + mi * 16 + lk * 4 + r;
            dst0[((size_t)bh * 2048 + tt0 + ml) * 128 + dh] =
                f2bf(acc[mi][ni][r] + bv);
          }
        }
      }
    } else {
      // v: stage n-major in LDS, then coalesced transposed write-out.
      const int h = (bn0 >> 7) & 7;
      const int bb = bm0 >> 11;
      const int bh = bb * 8 + h;
      const int tt0 = bm0 & 2047;
#pragma unroll
      for (int ni = 0; ni < 4; ni++) {
        const int nl = nh + ni * 16 + lm;
        const float bv = bias[bn0 + nl];
#pragma unroll
        for (int mi = 0; mi < 4; mi++) {
          const int ml = mh + mi * 16 + lk * 4;
          s16x4 o;
          o[0] = f2bf(acc[mi][ni][0] + bv);
          o[1] = f2bf(acc[mi][ni][1] + bv);
          o[2] = f2bf(acc[mi][ni][2] + bv);
          o[3] = f2bf(acc[mi][ni][3] + bv);
          *(s16x4*)(sm.tv + nl * 136 + ml) = o;
        }
      }
      __syncthreads();
#pragma unroll
      for (int c = 0; c < 8; c++) {
        const int u = c * 256 + tid;
        const int n = u >> 4, ch = u & 15;
        s16x8 vv = *(const s16x8*)(sm.tv + n * 136 + ch * 8);
        *(s16x8*)(vt16 + ((size_t)(bh * 128 + n)) * 2048 + tt0 + ch * 8) = vv;
      }
    }
  } else {
#pragma unroll
    for (int ni = 0; ni < 4; ni++) {
      const int n = n0 + ni * 16 + lm;
      const float bv = bias[n];
#pragma unroll
      for (int mi = 0; mi < 4; mi++) {
#pragma unroll
        for (int r = 0; r < 4; r++) {
          const int m = m0 + mi * 16 + lk * 4 + r;
          outf[(size_t)m * N + n] = acc[mi][ni][r] + bv;
        }
      }
    }
  }
}

// ---------------------------------------------------------------------------
// splat: q/k weights via MFMA against centers (1024 blocks) — R10 exact.
// ---------------------------------------------------------------------------
__global__ __launch_bounds__(256) void splat_tv(
    const short* __restrict__ q16, const short* __restrict__ k16,
    const short* __restrict__ c16, const float* __restrict__ csq,
    const float* __restrict__ inv2, const float* __restrict__ amp,
    short* __restrict__ qa16, short* __restrict__ kw16) {
  const int tid = threadIdx.x;
  const int it = blockIdx.x & 31;
  const int bh = (blockIdx.x >> 5) & 15;
  const int which = blockIdx.x >> 9;
  const int w = tid >> 6, l = tid & 63;
  const int lm = l & 15, lk = l >> 4;
  const int h = bh & 7;
  const int i0 = it * 64 + w * 16;
  const short* src = which ? k16 : q16;

  s16x8 af[4];
  float sq = 0.f;
#pragma unroll
  for (int kk = 0; kk < 4; kk++) {
    af[kk] = *(const s16x8*)(src + ((size_t)bh * 2048 + i0 + lm) * 128 + kk * 32 + lk * 8);
#pragma unroll
    for (int j = 0; j < 8; j++) {
      float f = bf2f(af[kk][j]);
      sq += f * f;
    }
  }
  sq += __shfl_xor(sq, 16);
  sq += __shfl_xor(sq, 32);

  f32x4 acc[2];
  acc[0] = (f32x4){0.f, 0.f, 0.f, 0.f};
  acc[1] = (f32x4){0.f, 0.f, 0.f, 0.f};
#pragma unroll
  for (int kk = 0; kk < 4; kk++) {
    s16x8 b0 = *(const s16x8*)(c16 + (size_t)(h * 32 + lm) * 128 + kk * 32 + lk * 8);
    s16x8 b1 = *(const s16x8*)(c16 + (size_t)(h * 32 + 16 + lm) * 128 + kk * 32 + lk * 8);
    acc[0] = MFMA_BF16(af[kk], b0, acc[0]);
    acc[1] = MFMA_BF16(af[kk], b1, acc[1]);
  }
  short* dst = which ? kw16 : qa16;
#pragma unroll
  for (int ni = 0; ni < 2; ni++) {
    const int n = ni * 16 + lm;
    const float cs = csq[h * 32 + n];
    const float iv2 = inv2[h * 32 + n];
    const float am = which ? 1.0f : amp[h * 32 + n];
#pragma unroll
    for (int r = 0; r < 4; r++) {
      float qs = __shfl(sq, lk * 4 + r);
      float d2 = fmaxf(qs + cs - 2.0f * acc[ni][r], 0.0f);
      float wv = __expf(iv2 * d2) * am;
      int m = i0 + lk * 4 + r;
      dst[((size_t)bh * 2048 + m) * 32 + n] = f2bf(wv);
    }
  }
}

// ---------------------------------------------------------------------------
// Flash attention v11 (R9 exact): sigma-relabeled swapped-QK + LDS-staged V
// dbuf, full j-range, fused normalize -> direct aout16/lrow write.
// ---------------------------------------------------------------------------
__global__ __launch_bounds__(256) void attn_flash(
    const short* __restrict__ qa16, const short* __restrict__ kw16,
    const short* __restrict__ vt16, const float* __restrict__ temp,
    float* __restrict__ lrow, short* __restrict__ aout16) {
  __shared__ short Vs[2][8192];  // 2 x 16KB: [128 rows][8 slots of 16B]
  const int tid = threadIdx.x;
  const int w = tid >> 6, l = tid & 63;
  const int lm = l & 15, lk = l >> 4;
  const int it = blockIdx.x, h = blockIdx.y;
  const int b = blockIdx.z;
  const int bh = b * 8 + h;
  const int i0 = it * 64 + w * 16;
  const float invT = 1.0f / temp[0];
  const short* kwb = kw16 + (size_t)bh * 2048 * 32;
  const short* vtb = vt16 + (size_t)bh * 128 * 2048;
  s16x8 qfrag = *(const s16x8*)(qa16 + ((size_t)(bh * 2048 + i0 + lm)) * 32 + lk * 8);
  float lsum = 0.f;
  f32x4 acc[8];
#pragma unroll
  for (int d = 0; d < 8; d++) acc[d] = (f32x4){0.f, 0.f, 0.f, 0.f};

  const int sig0 = (lm >> 2) * 8 + (lm & 3);
  const int srow8 = l >> 3;
  const int scb = (l & 7) ^ srow8;
  const int rcb0 = (lk ^ (lm & 7)) * 8;
  const int rcb1 = ((lk + 4) ^ (lm & 7)) * 8;

#pragma unroll
  for (int q = 0; q < 4; q++) {
    const int chunk = w * 4 + q;
    GLOAD_LDS16(vtb + (size_t)(chunk * 8 + srow8) * 2048 + scb * 8,
                &Vs[0][chunk * 512]);
  }
  __syncthreads();

  int cur = 0;
  for (int jc = 0; jc < 2048; jc += 64) {
    if (jc + 64 < 2048) {
#pragma unroll
      for (int q = 0; q < 4; q++) {
        const int chunk = w * 4 + q;
        GLOAD_LDS16(vtb + (size_t)(chunk * 8 + srow8) * 2048 + (jc + 64) + scb * 8,
                    &Vs[cur ^ 1][chunk * 512]);
      }
    }
    s16x8 kb[4];
    kb[0] = *(const s16x8*)(kwb + (size_t)(jc + sig0) * 32 + lk * 8);
    kb[1] = *(const s16x8*)(kwb + (size_t)(jc + sig0 + 4) * 32 + lk * 8);
    kb[2] = *(const s16x8*)(kwb + (size_t)(jc + sig0 + 32) * 32 + lk * 8);
    kb[3] = *(const s16x8*)(kwb + (size_t)(jc + sig0 + 36) * 32 + lk * 8);
    f32x4 z = (f32x4){0.f, 0.f, 0.f, 0.f};
    f32x4 s[4];
#pragma unroll
    for (int c = 0; c < 4; c++) s[c] = MFMA_BF16(kb[c], qfrag, z);
    float p[4][4];
#pragma unroll
    for (int c = 0; c < 4; c++) {
      p[c][0] = __expf(s[c][0] * invT);
      p[c][1] = __expf(s[c][1] * invT);
      p[c][2] = __expf(s[c][2] * invT);
      p[c][3] = __expf(s[c][3] * invT);
      lsum += (p[c][0] + p[c][1]) + (p[c][2] + p[c][3]);
    }
    union { unsigned u[4]; s16x8 v; } t0, t1;
    t0.u[0] = cvt_pk_bf16(p[0][0], p[0][1]);
    t0.u[1] = cvt_pk_bf16(p[0][2], p[0][3]);
    t0.u[2] = cvt_pk_bf16(p[1][0], p[1][1]);
    t0.u[3] = cvt_pk_bf16(p[1][2], p[1][3]);
    t1.u[0] = cvt_pk_bf16(p[2][0], p[2][1]);
    t1.u[1] = cvt_pk_bf16(p[2][2], p[2][3]);
    t1.u[2] = cvt_pk_bf16(p[3][0], p[3][1]);
    t1.u[3] = cvt_pk_bf16(p[3][2], p[3][3]);
    s16x8 pf0 = t0.v, pf1 = t1.v;
    const short* vb = Vs[cur];
#pragma unroll
    for (int d = 0; d < 8; d++) {
      const short* vsrow = vb + (d * 16 + lm) * 64;
      s16x8 vb0 = *(const s16x8*)(vsrow + rcb0);
      s16x8 vb1 = *(const s16x8*)(vsrow + rcb1);
      acc[d] = MFMA_BF16(pf0, vb0, acc[d]);
      acc[d] = MFMA_BF16(pf1, vb1, acc[d]);
    }
    __syncthreads();
    cur ^= 1;
  }
  lsum += __shfl_xor(lsum, 16);
  lsum += __shfl_xor(lsum, 32);
  if (l < 16) lrow[bh * 2048 + i0 + l] = lsum;
  float invl[4];
#pragma unroll
  for (int r = 0; r < 4; r++) invl[r] = 1.0f / __shfl(lsum, lk * 4 + r);
  short* ob = aout16 + ((size_t)(b * 2048 + i0)) * 1024 + h * 128 + lm;
#pragma unroll
  for (int r = 0; r < 4; r++) {
    const int row = lk * 4 + r;
#pragma unroll
    for (int d = 0; d < 8; d++)
      ob[(size_t)row * 1024 + d * 16] = f2bf(acc[d][r] * invl[r]);
  }
}

// ---------------------------------------------------------------------------
// gemm_out: standalone out-projection (R5 exact).
// ---------------------------------------------------------------------------
__global__ __launch_bounds__(256) void gemm_out(
    const short* __restrict__ aout16, const short* __restrict__ Wot16,
    const float* __restrict__ bout, float* __restrict__ out) {
  __shared__ short As[128 * 64];
  __shared__ short Bs[128 * 64];
  const int tid = threadIdx.x;
  const int w = tid >> 6, l = tid & 63;
  const int lm = l & 15, lk = l >> 4;
  const int idx = blockIdx.x;
  const int bn0 = (idx & 7) * 128;
  const int bm0 = (idx >> 3) * 128;
  const int n0 = bn0 + (w & 1) * 64;
  const int m0 = bm0 + (w >> 1) * 64;
  const int K = 1024;
  f32x4 acc[4][4];
#pragma unroll
  for (int mi = 0; mi < 4; mi++)
#pragma unroll
    for (int ni = 0; ni < 4; ni++) acc[mi][ni] = (f32x4){0.f, 0.f, 0.f, 0.f};
  const int srow = l >> 3;
  const int scol = (l & 7) * 8;
  const int mh = (w >> 1) * 64, nh = (w & 1) * 64;
  for (int k0 = 0; k0 < K; k0 += 64) {
#pragma unroll
    for (int q = 0; q < 4; q++) {
      const int chunk = w * 4 + q;
      const int row = chunk * 8 + srow;
      GLOAD_LDS16(aout16 + (size_t)(bm0 + row) * K + k0 + scol, As + chunk * 512);
      GLOAD_LDS16(Wot16 + (size_t)(bn0 + row) * K + k0 + scol, Bs + chunk * 512);
    }
    __syncthreads();
#pragma unroll
    for (int kk = 0; kk < 2; kk++) {
      s16x8 af[4], bf[4];
#pragma unroll
      for (int i = 0; i < 4; i++) {
        af[i] = *(const s16x8*)(As + (mh + i * 16 + lm) * 64 + kk * 32 + lk * 8);
        bf[i] = *(const s16x8*)(Bs + (nh + i * 16 + lm) * 64 + kk * 32 + lk * 8);
      }
#pragma unroll
      for (int mi = 0; mi < 4; mi++)
#pragma unroll
        for (int ni = 0; ni < 4; ni++)
          acc[mi][ni] = MFMA_BF16(af[mi], bf[ni], acc[mi][ni]);
    }
    __syncthreads();
  }
#pragma unroll
  for (int ni = 0; ni < 4; ni++) {
    const int n = n0 + ni * 16 + lm;
    const float bv = bout[n];
#pragma unroll
    for (int mi = 0; mi < 4; mi++) {
#pragma unroll
      for (int r = 0; r < 4; r++) {
        const int m = m0 + mi * 16 + lk * 4 + r;
        out[(size_t)m * 1024 + n] = acc[mi][ni][r] + bv;
      }
    }
  }
}

// ---------------------------------------------------------------------------
// attn_write: standalone, 16x32 tiles (R5 exact).
// ---------------------------------------------------------------------------
__global__ __launch_bounds__(256) void attn_write(
    const short* __restrict__ qa16, const short* __restrict__ kw16,
    const float* __restrict__ lrow, const float* __restrict__ temp,
    float* __restrict__ attn) {
  __shared__ float pl[8][16][33];
  const int tid = threadIdx.x;
  const int w = tid >> 6, l = tid & 63;
  const int lm = l & 15, lk = l >> 4;
  const int bx = blockIdx.x;
  const int i0 = (bx & 127) * 16;
  const int j0 = ((bx >> 7) & 63) * 32;
  const int b = bx >> 13;
  const float invT = 1.0f / temp[0];
#pragma unroll
  for (int hh = 0; hh < 2; hh++) {
    const int h = w * 2 + hh;
    const int bh = b * 8 + h;
    s16x8 qf = *(const s16x8*)(qa16 + ((size_t)(bh * 2048 + i0 + lm)) * 32 + lk * 8);
    s16x8 kf[2];
#pragma unroll
    for (int jh = 0; jh < 2; jh++)
      kf[jh] = *(const s16x8*)(kw16 + ((size_t)(bh * 2048 + j0 + jh * 16 + lm)) * 32 + lk * 8);
    float il[4];
#pragma unroll
    for (int r = 0; r < 4; r++)
      il[r] = 1.0f / lrow[bh * 2048 + i0 + lk * 4 + r];
    f32x4 z = (f32x4){0.f, 0.f, 0.f, 0.f};
#pragma unroll
    for (int jh = 0; jh < 2; jh++) {
      f32x4 s = MFMA_BF16(qf, kf[jh], z);
#pragma unroll
      for (int r = 0; r < 4; r++) {
        float p = __expf(s[r] * invT) * il[r];
        pl[h][lk * 4 + r][jh * 16 + lm] = p;
      }
    }
  }
  __syncthreads();
#pragma unroll
  for (int c = 0; c < 4; c++) {
    int u = c * 256 + tid;
    int i = u >> 6, rem = u & 63;
    int j = rem >> 1, h4 = (rem & 1) * 4;
    f32x4 v;
    v[0] = pl[h4][i][j];
    v[1] = pl[h4 + 1][i][j];
    v[2] = pl[h4 + 2][i][j];
    v[3] = pl[h4 + 3][i][j];
    f32x4* dst = (f32x4*)(attn + (((size_t)(b * 2048 + i0 + i)) * 2048 + j0 + j) * 8 + h4);
    __builtin_nontemporal_store(v, dst);
  }
}

// ---------------------------------------------------------------------------
extern "C" void kernel_launch(void* const* d_in, const int* in_sizes, int n_in,
                              void* d_out, int out_size, void* d_ws, size_t ws_size,
                              hipStream_t stream) {
  const float* x    = (const float*)d_in[0];
  const float* Wqkv = (const float*)d_in[1];
  const float* bqkv = (const float*)d_in[2];
  const float* Wout = (const float*)d_in[3];
  const float* bout = (const float*)d_in[4];
  const float* ctr  = (const float*)d_in[5];
  const float* ls   = (const float*)d_in[6];
  const float* la   = (const float*)d_in[7];
  const float* temp = (const float*)d_in[8];

  float* out = (float*)d_out;                 // (B,T,D)
  float* attn = out + 4194304;                // (B,T,T,H)

  short* ws16 = (short*)d_ws;
  short* q16   = ws16;                        // 4,194,304 sh (B,H,T,Dh) bf16
  short* k16   = q16 + 4194304;               // 4,194,304 sh
  short* vt16  = k16 + 4194304;               // 4,194,304 sh (B,H,Dh,T) bf16
  short* x16   = vt16 + 4194304;              // 4,194,304 sh
  short* Wqt16 = x16 + 4194304;               // 3,145,728 sh
  short* Wot16 = Wqt16 + 3145728;             // 1,048,576 sh
  short* qa16  = Wot16 + 1048576;             // 1,048,576 sh
  short* kw16  = qa16 + 1048576;              // 1,048,576 sh
  short* aout16 = kw16 + 1048576;             // 4,194,304 sh
  short* c16   = aout16 + 4194304;            // 32,768 sh
  float* lrow  = (float*)(c16 + 32768);       // 32,768 fl
  float* csq   = lrow + 32768;                // 256
  float* inv2  = csq + 256;
  float* amp   = inv2 + 256;

  prep_fused<<<8193, 256, 0, stream>>>(x, x16, Wqkv, Wqt16, Wout, Wot16,
                                       ctr, ls, la, c16, csq, inv2, amp);
  gemm_bf16<3072, true><<<dim3(24, 32), 256, 0, stream>>>(
      x16, Wqt16, bqkv, q16, k16, vt16, nullptr);
  splat_tv<<<1024, 256, 0, stream>>>(
      q16, k16, c16, csq, inv2, amp, qa16, kw16);
  attn_flash<<<dim3(32, 8, 2), 256, 0, stream>>>(
      qa16, kw16, vt16, temp, lrow, aout16);
  gemm_out<<<256, 256, 0, stream>>>(aout16, Wot16, bout, out);
  attn_write<<<16384, 256, 0, stream>>>(qa16, kw16, lrow, temp, attn);
}

// Round 14
// 453.826 us; speedup vs baseline: 1.0420x; 1.0109x over previous
//
#include <hip/hip_runtime.h>
#include <math.h>

// Shapes: B=2, T=2048, D=1024, H=8, S=32, Dh=128, 3D=3072, B*T=4096
// POLISH R29 (resubmit — R13 bench was a GPUAcquisitionTimeout, no data).
// base = R12 (458.8us PASS). Single change: gemm_out re-tiled
// 128x128 -> 128(M)x64(N), 256 -> 512 blocks = 2 blocks/CU. At 1 block/CU
// (1 wave/SIMD) the 2-barrier K-loop was fully latency-exposed; 2 blocks/CU
// lets one block's MFMA cover the other's staging stall (m114 overlap).
// Staging/elem rises 1.5x but gemm_out traffic is only ~12MB (L2) — this
// kernel is latency-bound, not traffic-bound (R8's small-tile lesson applies
// to traffic-bound kernels only). Everything else R12-exact.

typedef __attribute__((ext_vector_type(8))) short s16x8;
typedef __attribute__((ext_vector_type(4))) short s16x4;
typedef __attribute__((ext_vector_type(4))) float f32x4;

__device__ inline short f2bf(float f) {
  union { float f; unsigned u; } v; v.f = f;
  unsigned r = v.u + 0x7FFFu + ((v.u >> 16) & 1u);
  return (short)(r >> 16);
}
__device__ inline float bf2f(short s) {
  union { unsigned u; float f; } v;
  v.u = ((unsigned)(unsigned short)s) << 16;
  return v.f;
}
// Packed f32x2 -> bf16x2, RNE (identical rounding to f2bf).
__device__ inline unsigned cvt_pk_bf16(float lo, float hi) {
  unsigned r;
  asm("v_cvt_pk_bf16_f32 %0, %1, %2" : "=v"(r) : "v"(lo), "v"(hi));
  return r;
}
#define MFMA_BF16(a, b, c) __builtin_amdgcn_mfma_f32_16x16x32_bf16((a), (b), (c), 0, 0, 0)

// Async global->LDS, 16B per lane. LDS dest is wave-uniform base + lane*16.
#define GLOAD_LDS16(gsrc, ldst)                                          \
  __builtin_amdgcn_global_load_lds(                                      \
      (const __attribute__((address_space(1))) void*)(gsrc),             \
      (__attribute__((address_space(3))) void*)(ldst), 16, 0, 0)

// ---------------------------------------------------------------------------
// Fused prep (round-8 exact).
// ---------------------------------------------------------------------------
__device__ inline void transpose_tile32(const float* __restrict__ W,
                                        short* __restrict__ Wt, int K, int N,
                                        int n0, int k0) {
  __shared__ float tile[32][33];
  const int r = threadIdx.x >> 3, c4 = (threadIdx.x & 7) * 4;
  float4 v = *(const float4*)(W + (size_t)(k0 + r) * N + n0 + c4);
  tile[r][c4 + 0] = v.x; tile[r][c4 + 1] = v.y;
  tile[r][c4 + 2] = v.z; tile[r][c4 + 3] = v.w;
  __syncthreads();
  s16x4 o;
  o[0] = f2bf(tile[c4 + 0][r]);
  o[1] = f2bf(tile[c4 + 1][r]);
  o[2] = f2bf(tile[c4 + 2][r]);
  o[3] = f2bf(tile[c4 + 3][r]);
  *(s16x4*)(Wt + (size_t)(n0 + r) * K + k0 + c4) = o;
}

__global__ __launch_bounds__(256) void prep_fused(
    const float* __restrict__ x, short* __restrict__ x16,
    const float* __restrict__ Wqkv, short* __restrict__ Wqt16,
    const float* __restrict__ Wout, short* __restrict__ Wot16,
    const float* __restrict__ ctr, const float* __restrict__ ls,
    const float* __restrict__ la, short* __restrict__ c16,
    float* __restrict__ csq, float* __restrict__ inv2, float* __restrict__ amp) {
  const int bx = blockIdx.x;
  if (bx < 4096) {
    int i = bx * 256 + threadIdx.x;
    float4 v = ((const float4*)x)[i];
    s16x4 o;
    o[0] = f2bf(v.x); o[1] = f2bf(v.y); o[2] = f2bf(v.z); o[3] = f2bf(v.w);
    ((s16x4*)x16)[i] = o;
  } else if (bx < 7168) {
    int idx = bx - 4096;
    transpose_tile32(Wqkv, Wqt16, 1024, 3072, (idx % 96) * 32, (idx / 96) * 32);
  } else if (bx < 8192) {
    int idx = bx - 7168;
    transpose_tile32(Wout, Wot16, 1024, 1024, (idx % 32) * 32, (idx / 32) * 32);
  } else {
    const int t = threadIdx.x;
    float sumsq = 0.f;
#pragma unroll
    for (int d = 0; d < 128; d += 4) {
      float4 v = *(const float4*)(ctr + (size_t)t * 128 + d);
      sumsq += v.x * v.x + v.y * v.y + v.z * v.z + v.w * v.w;
      s16x4 o;
      o[0] = f2bf(v.x); o[1] = f2bf(v.y); o[2] = f2bf(v.z); o[3] = f2bf(v.w);
      *(s16x4*)(c16 + (size_t)t * 128 + d) = o;
    }
    csq[t] = sumsq;
    float sc = __expf(ls[t]);
    float iv = 1.0f / (sc + 1e-6f);
    inv2[t] = -0.5f * iv * iv;
    amp[t] = __expf(la[t]);
  }
}

// ---------------------------------------------------------------------------
// bf16 MFMA GEMM, m97-style LDS staging — QKV (R12 exact).
// q/k: direct row-major bf16 stores. v: LDS-transposed coalesced s16x8 rows.
// ---------------------------------------------------------------------------
template <int N, bool SCATTER>
__global__ __launch_bounds__(256) void gemm_bf16(
    const short* __restrict__ A, const short* __restrict__ Wt,
    const float* __restrict__ bias,
    short* __restrict__ q16, short* __restrict__ k16, short* __restrict__ vt16,
    float* __restrict__ outf) {
  __shared__ union {
    struct { short As[128 * 64]; short Bs[128 * 64]; } s;  // 32 KB
    short tv[128 * 136];                                   // 34 KB (v-transpose)
  } sm;
  const int tid = threadIdx.x;
  const int w = tid >> 6, l = tid & 63;
  const int lm = l & 15, lk = l >> 4;
  const int bn0 = blockIdx.x * 128;
  const int bm0 = blockIdx.y * 128;
  const int n0 = bn0 + (w & 1) * 64;
  const int m0 = bm0 + (w >> 1) * 64;
  const int K = 1024;
  f32x4 acc[4][4];
#pragma unroll
  for (int mi = 0; mi < 4; mi++)
#pragma unroll
    for (int ni = 0; ni < 4; ni++) acc[mi][ni] = (f32x4){0.f, 0.f, 0.f, 0.f};

  const int srow = l >> 3;
  const int scol = (l & 7) * 8;
  const int mh = (w >> 1) * 64, nh = (w & 1) * 64;

  for (int k0 = 0; k0 < K; k0 += 64) {
#pragma unroll
    for (int q = 0; q < 4; q++) {
      const int chunk = w * 4 + q;
      const int row = chunk * 8 + srow;
      GLOAD_LDS16(A + (size_t)(bm0 + row) * K + k0 + scol, sm.s.As + chunk * 512);
      GLOAD_LDS16(Wt + (size_t)(bn0 + row) * K + k0 + scol, sm.s.Bs + chunk * 512);
    }
    __syncthreads();
#pragma unroll
    for (int kk = 0; kk < 2; kk++) {
      s16x8 af[4], bf[4];
#pragma unroll
      for (int i = 0; i < 4; i++) {
        af[i] = *(const s16x8*)(sm.s.As + (mh + i * 16 + lm) * 64 + kk * 32 + lk * 8);
        bf[i] = *(const s16x8*)(sm.s.Bs + (nh + i * 16 + lm) * 64 + kk * 32 + lk * 8);
      }
#pragma unroll
      for (int mi = 0; mi < 4; mi++)
#pragma unroll
        for (int ni = 0; ni < 4; ni++)
          acc[mi][ni] = MFMA_BF16(af[mi], bf[ni], acc[mi][ni]);
    }
    __syncthreads();
  }
  if (SCATTER) {
    const int three = bn0 >> 10;
    if (three < 2) {
      // q/k: direct row-major bf16 stores (R10 path, proven).
      short* dst0 = three ? k16 : q16;
      const int h = (bn0 >> 7) & 7;
      const int bb = bm0 >> 11;
      const int bh = bb * 8 + h;
      const int tt0 = bm0 & 2047;
#pragma unroll
      for (int ni = 0; ni < 4; ni++) {
        const int n = n0 + ni * 16 + lm;
        const int dh = n & 127;
        const float bv = bias[n];
#pragma unroll
        for (int mi = 0; mi < 4; mi++) {
#pragma unroll
          for (int r = 0; r < 4; r++) {
            const int ml = mh + mi * 16 + lk * 4 + r;
            dst0[((size_t)bh * 2048 + tt0 + ml) * 128 + dh] =
                f2bf(acc[mi][ni][r] + bv);
          }
        }
      }
    } else {
      // v: stage n-major in LDS, then coalesced transposed write-out.
      const int h = (bn0 >> 7) & 7;
      const int bb = bm0 >> 11;
      const int bh = bb * 8 + h;
      const int tt0 = bm0 & 2047;
#pragma unroll
      for (int ni = 0; ni < 4; ni++) {
        const int nl = nh + ni * 16 + lm;
        const float bv = bias[bn0 + nl];
#pragma unroll
        for (int mi = 0; mi < 4; mi++) {
          const int ml = mh + mi * 16 + lk * 4;
          s16x4 o;
          o[0] = f2bf(acc[mi][ni][0] + bv);
          o[1] = f2bf(acc[mi][ni][1] + bv);
          o[2] = f2bf(acc[mi][ni][2] + bv);
          o[3] = f2bf(acc[mi][ni][3] + bv);
          *(s16x4*)(sm.tv + nl * 136 + ml) = o;
        }
      }
      __syncthreads();
#pragma unroll
      for (int c = 0; c < 8; c++) {
        const int u = c * 256 + tid;
        const int n = u >> 4, ch = u & 15;
        s16x8 vv = *(const s16x8*)(sm.tv + n * 136 + ch * 8);
        *(s16x8*)(vt16 + ((size_t)(bh * 128 + n)) * 2048 + tt0 + ch * 8) = vv;
      }
    }
  } else {
#pragma unroll
    for (int ni = 0; ni < 4; ni++) {
      const int n = n0 + ni * 16 + lm;
      const float bv = bias[n];
#pragma unroll
      for (int mi = 0; mi < 4; mi++) {
#pragma unroll
        for (int r = 0; r < 4; r++) {
          const int m = m0 + mi * 16 + lk * 4 + r;
          outf[(size_t)m * N + n] = acc[mi][ni][r] + bv;
        }
      }
    }
  }
}

// ---------------------------------------------------------------------------
// splat: q/k weights via MFMA against centers (1024 blocks) — R12 exact.
// ---------------------------------------------------------------------------
__global__ __launch_bounds__(256) void splat_tv(
    const short* __restrict__ q16, const short* __restrict__ k16,
    const short* __restrict__ c16, const float* __restrict__ csq,
    const float* __restrict__ inv2, const float* __restrict__ amp,
    short* __restrict__ qa16, short* __restrict__ kw16) {
  const int tid = threadIdx.x;
  const int it = blockIdx.x & 31;
  const int bh = (blockIdx.x >> 5) & 15;
  const int which = blockIdx.x >> 9;
  const int w = tid >> 6, l = tid & 63;
  const int lm = l & 15, lk = l >> 4;
  const int h = bh & 7;
  const int i0 = it * 64 + w * 16;
  const short* src = which ? k16 : q16;

  s16x8 af[4];
  float sq = 0.f;
#pragma unroll
  for (int kk = 0; kk < 4; kk++) {
    af[kk] = *(const s16x8*)(src + ((size_t)bh * 2048 + i0 + lm) * 128 + kk * 32 + lk * 8);
#pragma unroll
    for (int j = 0; j < 8; j++) {
      float f = bf2f(af[kk][j]);
      sq += f * f;
    }
  }
  sq += __shfl_xor(sq, 16);
  sq += __shfl_xor(sq, 32);

  f32x4 acc[2];
  acc[0] = (f32x4){0.f, 0.f, 0.f, 0.f};
  acc[1] = (f32x4){0.f, 0.f, 0.f, 0.f};
#pragma unroll
  for (int kk = 0; kk < 4; kk++) {
    s16x8 b0 = *(const s16x8*)(c16 + (size_t)(h * 32 + lm) * 128 + kk * 32 + lk * 8);
    s16x8 b1 = *(const s16x8*)(c16 + (size_t)(h * 32 + 16 + lm) * 128 + kk * 32 + lk * 8);
    acc[0] = MFMA_BF16(af[kk], b0, acc[0]);
    acc[1] = MFMA_BF16(af[kk], b1, acc[1]);
  }
  short* dst = which ? kw16 : qa16;
#pragma unroll
  for (int ni = 0; ni < 2; ni++) {
    const int n = ni * 16 + lm;
    const float cs = csq[h * 32 + n];
    const float iv2 = inv2[h * 32 + n];
    const float am = which ? 1.0f : amp[h * 32 + n];
#pragma unroll
    for (int r = 0; r < 4; r++) {
      float qs = __shfl(sq, lk * 4 + r);
      float d2 = fmaxf(qs + cs - 2.0f * acc[ni][r], 0.0f);
      float wv = __expf(iv2 * d2) * am;
      int m = i0 + lk * 4 + r;
      dst[((size_t)bh * 2048 + m) * 32 + n] = f2bf(wv);
    }
  }
}

// ---------------------------------------------------------------------------
// Flash attention v11 (R12 exact): sigma-relabeled swapped-QK + LDS-staged V
// dbuf, full j-range, fused normalize -> direct aout16/lrow write.
// ---------------------------------------------------------------------------
__global__ __launch_bounds__(256) void attn_flash(
    const short* __restrict__ qa16, const short* __restrict__ kw16,
    const short* __restrict__ vt16, const float* __restrict__ temp,
    float* __restrict__ lrow, short* __restrict__ aout16) {
  __shared__ short Vs[2][8192];  // 2 x 16KB: [128 rows][8 slots of 16B]
  const int tid = threadIdx.x;
  const int w = tid >> 6, l = tid & 63;
  const int lm = l & 15, lk = l >> 4;
  const int it = blockIdx.x, h = blockIdx.y;
  const int b = blockIdx.z;
  const int bh = b * 8 + h;
  const int i0 = it * 64 + w * 16;
  const float invT = 1.0f / temp[0];
  const short* kwb = kw16 + (size_t)bh * 2048 * 32;
  const short* vtb = vt16 + (size_t)bh * 128 * 2048;
  s16x8 qfrag = *(const s16x8*)(qa16 + ((size_t)(bh * 2048 + i0 + lm)) * 32 + lk * 8);
  float lsum = 0.f;
  f32x4 acc[8];
#pragma unroll
  for (int d = 0; d < 8; d++) acc[d] = (f32x4){0.f, 0.f, 0.f, 0.f};

  const int sig0 = (lm >> 2) * 8 + (lm & 3);
  const int srow8 = l >> 3;
  const int scb = (l & 7) ^ srow8;
  const int rcb0 = (lk ^ (lm & 7)) * 8;
  const int rcb1 = ((lk + 4) ^ (lm & 7)) * 8;

#pragma unroll
  for (int q = 0; q < 4; q++) {
    const int chunk = w * 4 + q;
    GLOAD_LDS16(vtb + (size_t)(chunk * 8 + srow8) * 2048 + scb * 8,
                &Vs[0][chunk * 512]);
  }
  __syncthreads();

  int cur = 0;
  for (int jc = 0; jc < 2048; jc += 64) {
    if (jc + 64 < 2048) {
#pragma unroll
      for (int q = 0; q < 4; q++) {
        const int chunk = w * 4 + q;
        GLOAD_LDS16(vtb + (size_t)(chunk * 8 + srow8) * 2048 + (jc + 64) + scb * 8,
                    &Vs[cur ^ 1][chunk * 512]);
      }
    }
    s16x8 kb[4];
    kb[0] = *(const s16x8*)(kwb + (size_t)(jc + sig0) * 32 + lk * 8);
    kb[1] = *(const s16x8*)(kwb + (size_t)(jc + sig0 + 4) * 32 + lk * 8);
    kb[2] = *(const s16x8*)(kwb + (size_t)(jc + sig0 + 32) * 32 + lk * 8);
    kb[3] = *(const s16x8*)(kwb + (size_t)(jc + sig0 + 36) * 32 + lk * 8);
    f32x4 z = (f32x4){0.f, 0.f, 0.f, 0.f};
    f32x4 s[4];
#pragma unroll
    for (int c = 0; c < 4; c++) s[c] = MFMA_BF16(kb[c], qfrag, z);
    float p[4][4];
#pragma unroll
    for (int c = 0; c < 4; c++) {
      p[c][0] = __expf(s[c][0] * invT);
      p[c][1] = __expf(s[c][1] * invT);
      p[c][2] = __expf(s[c][2] * invT);
      p[c][3] = __expf(s[c][3] * invT);
      lsum += (p[c][0] + p[c][1]) + (p[c][2] + p[c][3]);
    }
    union { unsigned u[4]; s16x8 v; } t0, t1;
    t0.u[0] = cvt_pk_bf16(p[0][0], p[0][1]);
    t0.u[1] = cvt_pk_bf16(p[0][2], p[0][3]);
    t0.u[2] = cvt_pk_bf16(p[1][0], p[1][1]);
    t0.u[3] = cvt_pk_bf16(p[1][2], p[1][3]);
    t1.u[0] = cvt_pk_bf16(p[2][0], p[2][1]);
    t1.u[1] = cvt_pk_bf16(p[2][2], p[2][3]);
    t1.u[2] = cvt_pk_bf16(p[3][0], p[3][1]);
    t1.u[3] = cvt_pk_bf16(p[3][2], p[3][3]);
    s16x8 pf0 = t0.v, pf1 = t1.v;
    const short* vb = Vs[cur];
#pragma unroll
    for (int d = 0; d < 8; d++) {
      const short* vsrow = vb + (d * 16 + lm) * 64;
      s16x8 vb0 = *(const s16x8*)(vsrow + rcb0);
      s16x8 vb1 = *(const s16x8*)(vsrow + rcb1);
      acc[d] = MFMA_BF16(pf0, vb0, acc[d]);
      acc[d] = MFMA_BF16(pf1, vb1, acc[d]);
    }
    __syncthreads();
    cur ^= 1;
  }
  lsum += __shfl_xor(lsum, 16);
  lsum += __shfl_xor(lsum, 32);
  if (l < 16) lrow[bh * 2048 + i0 + l] = lsum;
  float invl[4];
#pragma unroll
  for (int r = 0; r < 4; r++) invl[r] = 1.0f / __shfl(lsum, lk * 4 + r);
  short* ob = aout16 + ((size_t)(b * 2048 + i0)) * 1024 + h * 128 + lm;
#pragma unroll
  for (int r = 0; r < 4; r++) {
    const int row = lk * 4 + r;
#pragma unroll
    for (int d = 0; d < 8; d++)
      ob[(size_t)row * 1024 + d * 16] = f2bf(acc[d][r] * invl[r]);
  }
}

// ---------------------------------------------------------------------------
// gemm_out: 128(M)x64(N) tiles, 512 blocks = 2 blocks/CU.
// Same staging/fragment/epilogue structure, halved N per block.
// ---------------------------------------------------------------------------
__global__ __launch_bounds__(256) void gemm_out(
    const short* __restrict__ aout16, const short* __restrict__ Wot16,
    const float* __restrict__ bout, float* __restrict__ out) {
  __shared__ short As[128 * 64];   // 16 KB
  __shared__ short Bs[64 * 64];    // 8 KB
  const int tid = threadIdx.x;
  const int w = tid >> 6, l = tid & 63;
  const int lm = l & 15, lk = l >> 4;
  const int idx = blockIdx.x;
  const int bn0 = (idx & 15) * 64;
  const int bm0 = (idx >> 4) * 128;
  const int K = 1024;
  f32x4 acc[4][2];
#pragma unroll
  for (int mi = 0; mi < 4; mi++)
#pragma unroll
    for (int ni = 0; ni < 2; ni++) acc[mi][ni] = (f32x4){0.f, 0.f, 0.f, 0.f};
  const int srow = l >> 3;
  const int scol = (l & 7) * 8;
  const int mh = (w >> 1) * 64, nh = (w & 1) * 32;
  for (int k0 = 0; k0 < K; k0 += 64) {
#pragma unroll
    for (int q = 0; q < 4; q++) {
      const int chunk = w * 4 + q;                 // 0..15: 128 A-rows
      GLOAD_LDS16(aout16 + (size_t)(bm0 + chunk * 8 + srow) * K + k0 + scol,
                  As + chunk * 512);
    }
#pragma unroll
    for (int q = 0; q < 2; q++) {
      const int chunk = w * 2 + q;                 // 0..7: 64 B-rows
      GLOAD_LDS16(Wot16 + (size_t)(bn0 + chunk * 8 + srow) * K + k0 + scol,
                  Bs + chunk * 512);
    }
    __syncthreads();
#pragma unroll
    for (int kk = 0; kk < 2; kk++) {
      s16x8 af[4], bf[2];
#pragma unroll
      for (int i = 0; i < 4; i++)
        af[i] = *(const s16x8*)(As + (mh + i * 16 + lm) * 64 + kk * 32 + lk * 8);
#pragma unroll
      for (int i = 0; i < 2; i++)
        bf[i] = *(const s16x8*)(Bs + (nh + i * 16 + lm) * 64 + kk * 32 + lk * 8);
#pragma unroll
      for (int mi = 0; mi < 4; mi++)
#pragma unroll
        for (int ni = 0; ni < 2; ni++)
          acc[mi][ni] = MFMA_BF16(af[mi], bf[ni], acc[mi][ni]);
    }
    __syncthreads();
  }
#pragma unroll
  for (int ni = 0; ni < 2; ni++) {
    const int n = bn0 + nh + ni * 16 + lm;
    const float bv = bout[n];
#pragma unroll
    for (int mi = 0; mi < 4; mi++) {
#pragma unroll
      for (int r = 0; r < 4; r++) {
        const int m = bm0 + mh + mi * 16 + lk * 4 + r;
        out[(size_t)m * 1024 + n] = acc[mi][ni][r] + bv;
      }
    }
  }
}

// ---------------------------------------------------------------------------
// attn_write: standalone, 16x32 tiles (R12 exact).
// ---------------------------------------------------------------------------
__global__ __launch_bounds__(256) void attn_write(
    const short* __restrict__ qa16, const short* __restrict__ kw16,
    const float* __restrict__ lrow, const float* __restrict__ temp,
    float* __restrict__ attn) {
  __shared__ float pl[8][16][33];
  const int tid = threadIdx.x;
  const int w = tid >> 6, l = tid & 63;
  const int lm = l & 15, lk = l >> 4;
  const int bx = blockIdx.x;
  const int i0 = (bx & 127) * 16;
  const int j0 = ((bx >> 7) & 63) * 32;
  const int b = bx >> 13;
  const float invT = 1.0f / temp[0];
#pragma unroll
  for (int hh = 0; hh < 2; hh++) {
    const int h = w * 2 + hh;
    const int bh = b * 8 + h;
    s16x8 qf = *(const s16x8*)(qa16 + ((size_t)(bh * 2048 + i0 + lm)) * 32 + lk * 8);
    s16x8 kf[2];
#pragma unroll
    for (int jh = 0; jh < 2; jh++)
      kf[jh] = *(const s16x8*)(kw16 + ((size_t)(bh * 2048 + j0 + jh * 16 + lm)) * 32 + lk * 8);
    float il[4];
#pragma unroll
    for (int r = 0; r < 4; r++)
      il[r] = 1.0f / lrow[bh * 2048 + i0 + lk * 4 + r];
    f32x4 z = (f32x4){0.f, 0.f, 0.f, 0.f};
#pragma unroll
    for (int jh = 0; jh < 2; jh++) {
      f32x4 s = MFMA_BF16(qf, kf[jh], z);
#pragma unroll
      for (int r = 0; r < 4; r++) {
        float p = __expf(s[r] * invT) * il[r];
        pl[h][lk * 4 + r][jh * 16 + lm] = p;
      }
    }
  }
  __syncthreads();
#pragma unroll
  for (int c = 0; c < 4; c++) {
    int u = c * 256 + tid;
    int i = u >> 6, rem = u & 63;
    int j = rem >> 1, h4 = (rem & 1) * 4;
    f32x4 v;
    v[0] = pl[h4][i][j];
    v[1] = pl[h4 + 1][i][j];
    v[2] = pl[h4 + 2][i][j];
    v[3] = pl[h4 + 3][i][j];
    f32x4* dst = (f32x4*)(attn + (((size_t)(b * 2048 + i0 + i)) * 2048 + j0 + j) * 8 + h4);
    __builtin_nontemporal_store(v, dst);
  }
}

// ---------------------------------------------------------------------------
extern "C" void kernel_launch(void* const* d_in, const int* in_sizes, int n_in,
                              void* d_out, int out_size, void* d_ws, size_t ws_size,
                              hipStream_t stream) {
  const float* x    = (const float*)d_in[0];
  const float* Wqkv = (const float*)d_in[1];
  const float* bqkv = (const float*)d_in[2];
  const float* Wout = (const float*)d_in[3];
  const float* bout = (const float*)d_in[4];
  const float* ctr  = (const float*)d_in[5];
  const float* ls   = (const float*)d_in[6];
  const float* la   = (const float*)d_in[7];
  const float* temp = (const float*)d_in[8];

  float* out = (float*)d_out;                 // (B,T,D)
  float* attn = out + 4194304;                // (B,T,T,H)

  short* ws16 = (short*)d_ws;
  short* q16   = ws16;                        // 4,194,304 sh (B,H,T,Dh) bf16
  short* k16   = q16 + 4194304;               // 4,194,304 sh
  short* vt16  = k16 + 4194304;               // 4,194,304 sh (B,H,Dh,T) bf16
  short* x16   = vt16 + 4194304;              // 4,194,304 sh
  short* Wqt16 = x16 + 4194304;               // 3,145,728 sh
  short* Wot16 = Wqt16 + 3145728;             // 1,048,576 sh
  short* qa16  = Wot16 + 1048576;             // 1,048,576 sh
  short* kw16  = qa16 + 1048576;              // 1,048,576 sh
  short* aout16 = kw16 + 1048576;             // 4,194,304 sh
  short* c16   = aout16 + 4194304;            // 32,768 sh
  float* lrow  = (float*)(c16 + 32768);       // 32,768 fl
  float* csq   = lrow + 32768;                // 256
  float* inv2  = csq + 256;
  float* amp   = inv2 + 256;

  prep_fused<<<8193, 256, 0, stream>>>(x, x16, Wqkv, Wqt16, Wout, Wot16,
                                       ctr, ls, la, c16, csq, inv2, amp);
  gemm_bf16<3072, true><<<dim3(24, 32), 256, 0, stream>>>(
      x16, Wqt16, bqkv, q16, k16, vt16, nullptr);
  splat_tv<<<1024, 256, 0, stream>>>(
      q16, k16, c16, csq, inv2, amp, qa16, kw16);
  attn_flash<<<dim3(32, 8, 2), 256, 0, stream>>>(
      qa16, kw16, vt16, temp, lrow, aout16);
  gemm_out<<<512, 256, 0, stream>>>(aout16, Wot16, bout, out);
  attn_write<<<16384, 256, 0, stream>>>(qa16, kw16, lrow, temp, attn);
}